// Round 1
// baseline (318.931 us; speedup 1.0000x reference)
//
#include <hip/hip_runtime.h>
#include <math.h>

// KDE via GEMM trick: density[i] = (1/M) * sum_j exp2(-C2*sq_ij - log2(M))
//   sq_ij = |x_i|^2 + |d_j|^2 - 2 * dot(x_i, d_j)
//   C2 = 0.5/sqrt(2*pi) * log2(e)
//
// Block = 256 threads (16x16), computes a 128x128 tile of the [N,M] pair
// matrix, 8x8 register micro-tile per thread. K=128 staged in 32-chunks into
// transposed LDS (stride 132: staging-write conflicts 8->4 way, inner reads
// conflict-free). Row/col norms computed from the staged tiles (no workspace).

#define D_DIM 128
#define BN 128
#define BM 128
#define KT 32
#define LDSS 132  // padded stride: +4 floats

__global__ __launch_bounds__(256, 4)
void kde_kernel(const float* __restrict__ x, const float* __restrict__ data,
                float* __restrict__ out, int N, int M) {
    __shared__ float xs[KT][LDSS];
    __shared__ float dsh[KT][LDSS];
    __shared__ float xn_s[BN];
    __shared__ float dn_s[BM];

    const int tid = threadIdx.x;
    const int ty = tid >> 4;   // 0..15 : row group (8 rows each)
    const int tx = tid & 15;   // 0..15 : col group (4+4 cols each)
    const int rowBase = blockIdx.y * BN;
    const int colBase = blockIdx.x * BM;

    float acc[8][8];
#pragma unroll
    for (int i = 0; i < 8; ++i)
#pragma unroll
        for (int j = 0; j < 8; ++j) acc[i][j] = 0.0f;

    float normAcc = 0.0f;  // tid<128: |x_row|^2 partial, else |d_col|^2 partial

    for (int kc = 0; kc < D_DIM; kc += KT) {
        __syncthreads();
        // Stage both tiles, transposed: [k][row]. 1024 float4 slots per side,
        // 4 per thread. Global: 8 consecutive lanes cover one row's 128B
        // k-segment (coalesced).
#pragma unroll
        for (int i = 0; i < 4; ++i) {
            const int idx = tid + i * 256;   // 0..1023
            const int row = idx >> 3;
            const int kq  = idx & 7;
            const float4 v = *(const float4*)&x[(size_t)(rowBase + row) * D_DIM + kc + kq * 4];
            xs[kq * 4 + 0][row] = v.x;
            xs[kq * 4 + 1][row] = v.y;
            xs[kq * 4 + 2][row] = v.z;
            xs[kq * 4 + 3][row] = v.w;
            const float4 w = *(const float4*)&data[(size_t)(colBase + row) * D_DIM + kc + kq * 4];
            dsh[kq * 4 + 0][row] = w.x;
            dsh[kq * 4 + 1][row] = w.y;
            dsh[kq * 4 + 2][row] = w.z;
            dsh[kq * 4 + 3][row] = w.w;
        }
        __syncthreads();

        // Norm partials from the staged tiles (stride LDSS => 2-way bank
        // alias only, free).
        {
            const float* col = (tid < 128) ? &xs[0][tid] : &dsh[0][tid - 128];
#pragma unroll
            for (int k = 0; k < KT; ++k) {
                const float v = col[k * LDSS];
                normAcc = fmaf(v, v, normAcc);
            }
        }

        // Main FMA loop: 64 FMA per k-step from 4 ds_read_b128.
#pragma unroll
        for (int k = 0; k < KT; ++k) {
            float a[8], b[8];
            *(float4*)&a[0] = *(const float4*)&xs[k][ty * 8];
            *(float4*)&a[4] = *(const float4*)&xs[k][ty * 8 + 4];
            *(float4*)&b[0] = *(const float4*)&dsh[k][tx * 4];
            *(float4*)&b[4] = *(const float4*)&dsh[k][64 + tx * 4];
#pragma unroll
            for (int i = 0; i < 8; ++i)
#pragma unroll
                for (int j = 0; j < 8; ++j)
                    acc[i][j] = fmaf(a[i], b[j], acc[i][j]);
        }
    }

    if (tid < 128) xn_s[tid] = normAcc;
    else           dn_s[tid - 128] = normAcc;
    __syncthreads();

    // exp2 constant: 0.5/sqrt(2*pi) * log2(e); /M folded as -log2(M).
    const float C2 = (float)(0.5 / 2.50662827463100050242 * 1.44269504088896340736);
    const float negLogM = -log2f((float)M);  // M=8192 -> exactly -13.0f

#pragma unroll
    for (int i = 0; i < 8; ++i) {
        const int row = ty * 8 + i;
        const float xnr = xn_s[row];
        float s = 0.0f;
#pragma unroll
        for (int j = 0; j < 8; ++j) {
            const int col = (j < 4) ? (tx * 4 + j) : (64 + tx * 4 + (j - 4));
            const float sq = xnr + dn_s[col] - 2.0f * acc[i][j];
            s += exp2f(fmaf(-C2, sq, negLogM));
        }
        // Reduce across the 16 col-threads sharing this row (contiguous
        // lanes: tid = ty*16+tx, xor of low 4 bits stays in-group).
#pragma unroll
        for (int off = 1; off < 16; off <<= 1)
            s += __shfl_xor(s, off, 64);
        if (tx == 0) atomicAdd(&out[rowBase + row], s);
    }
}

extern "C" void kernel_launch(void* const* d_in, const int* in_sizes, int n_in,
                              void* d_out, int out_size, void* d_ws, size_t ws_size,
                              hipStream_t stream) {
    const float* x    = (const float*)d_in[0];
    const float* data = (const float*)d_in[1];
    float* out = (float*)d_out;
    const int N = in_sizes[0] / D_DIM;
    const int M = in_sizes[1] / D_DIM;

    hipMemsetAsync(d_out, 0, (size_t)out_size * sizeof(float), stream);

    dim3 grid(M / BM, N / BN);
    kde_kernel<<<grid, 256, 0, stream>>>(x, data, out, N, M);
}

// Round 2
// 155.523 us; speedup vs baseline: 2.0507x; 2.0507x over previous
//
#include <hip/hip_runtime.h>
#include <math.h>

// KDE via GEMM trick, MFMA edition.
//   density[i] = (1/M) * sum_j exp2(-C2*sq_ij - log2(M))
//   sq_ij = |x_i|^2 + |d_j|^2 - 2 * dot(x_i, d_j)
//
// fp32 inputs are split x = hi + lo (bf16 each); dot = hi*hi + hi*lo + lo*hi
// via 3 chained mfma_f32_16x16x32_bf16 accumulations (lo*lo ~2^-18 dropped;
// norms are exact fp32 from a prep pass, so only the cross term is approx).
//
// Main kernel mirrors the verified m97 structure: 128x128 block tile, 4
// waves each 64x64 (4x4 grid of 16x16 MFMA tiles), K staged in 32-chunks via
// __builtin_amdgcn_global_load_lds width=16 into a fragment-major LDS layout
// (fragment f = t*64 + lane, 16 B each -> ds_read_b128 lane-sequential,
// conflict-free, and matches global_load_lds's base+lane*16 placement).
//
// Verified fragment mappings (learn_hip m89/m91/m118-122):
//   A: lane holds A[m=lane&15][k=(lane>>4)*8+j]   (x rows)
//   B: lane holds B[k=(lane>>4)*8+j][n=lane&15]   (= data rows, B^T row-major)
//   C/D: col=lane&15, row=(lane>>4)*4+reg

#define D_DIM 128

typedef __attribute__((ext_vector_type(8))) short short8;
typedef __attribute__((ext_vector_type(4))) float f32x4;

static __device__ __forceinline__ unsigned short f2bf(float f) {
    unsigned u = __builtin_bit_cast(unsigned, f);
    u += 0x7fffu + ((u >> 16) & 1u);   // RNE
    return (unsigned short)(u >> 16);
}
static __device__ __forceinline__ float bf2f(unsigned short h) {
    unsigned u = ((unsigned)h) << 16;
    return __builtin_bit_cast(float, u);
}

// ---------------- prep: fp32 -> (hi,lo) bf16 + exact fp32 row norms --------
__global__ __launch_bounds__(256)
void prep_kernel(const float* __restrict__ x, const float* __restrict__ data,
                 unsigned short* __restrict__ xh, unsigned short* __restrict__ xl,
                 unsigned short* __restrict__ dh, unsigned short* __restrict__ dl,
                 float* __restrict__ xn, float* __restrict__ dn, int xThreads) {
    const int gid = blockIdx.x * 256 + threadIdx.x;
    const int which = (gid >= xThreads);               // 0 -> x, 1 -> data
    const int id = which ? (gid - xThreads) : gid;
    const int row = id >> 5, seg = id & 31;            // 32 threads per row
    const float* src = which ? data : x;
    unsigned short* hh = which ? dh : xh;
    unsigned short* ll = which ? dl : xl;

    const float4 v = *(const float4*)&src[(size_t)row * D_DIM + seg * 4];
    ushort4 hv, lv;
    hv.x = f2bf(v.x); lv.x = f2bf(v.x - bf2f(hv.x));
    hv.y = f2bf(v.y); lv.y = f2bf(v.y - bf2f(hv.y));
    hv.z = f2bf(v.z); lv.z = f2bf(v.z - bf2f(hv.z));
    hv.w = f2bf(v.w); lv.w = f2bf(v.w - bf2f(hv.w));
    *(ushort4*)&hh[(size_t)row * D_DIM + seg * 4] = hv;
    *(ushort4*)&ll[(size_t)row * D_DIM + seg * 4] = lv;

    float nrm = v.x * v.x + v.y * v.y + v.z * v.z + v.w * v.w;
#pragma unroll
    for (int off = 1; off < 32; off <<= 1) nrm += __shfl_xor(nrm, off, 64);
    if (seg == 0) (which ? dn : xn)[row] = nrm;
}

// ---------------- main MFMA kernel ----------------------------------------
__global__ __launch_bounds__(256, 3)
void kde_mfma(const unsigned short* __restrict__ xh, const unsigned short* __restrict__ xl,
              const unsigned short* __restrict__ dh, const unsigned short* __restrict__ dl,
              const float* __restrict__ xn, const float* __restrict__ dn,
              float* __restrict__ out, float negLogM) {
    // 4 arrays (xh,xl,dh,dl) x 8 tiles x 64 fragments x 16 B = 32 KB
    __shared__ unsigned short lds[4][4096];
    __shared__ float xns[128], dns[128];

    const int tid  = threadIdx.x;
    const int lane = tid & 63;
    const int wv   = tid >> 6;
    const int q    = lane >> 4;     // 0..3
    const int r    = lane & 15;     // 0..15
    const int rowBase = blockIdx.y * 128;
    const int colBase = blockIdx.x * 128;
    const int wr = (wv >> 1) * 64;  // wave row offset in block tile
    const int wc = (wv & 1) * 64;   // wave col offset
    const int ta = wr >> 4;         // first row-tile index (0 or 4)
    const int tb = wc >> 4;         // first col-tile index (0 or 4)

    if (tid < 128) xns[tid] = xn[rowBase + tid];
    else           dns[tid - 128] = dn[colBase + tid - 128];

    f32x4 acc[4][4];
#pragma unroll
    for (int i = 0; i < 4; ++i)
#pragma unroll
        for (int j = 0; j < 4; ++j) acc[i][j] = (f32x4){0.f, 0.f, 0.f, 0.f};

    // Wave wv stages array wv: 8 tiles x 64 lanes of 16 B.
    const unsigned short* src = (wv == 0) ? xh : (wv == 1) ? xl : (wv == 2) ? dh : dl;
    const int rcBase = (wv < 2) ? rowBase : colBase;

    for (int kc = 0; kc < D_DIM; kc += 32) {
        __syncthreads();
#pragma unroll
        for (int t = 0; t < 8; ++t) {
            // lane reads global row (rcBase+t*16+r), k = kc + q*8 .. +7 (16 B)
            const unsigned short* g = &src[(size_t)(rcBase + t * 16 + r) * D_DIM + kc + q * 8];
            __builtin_amdgcn_global_load_lds(
                (const __attribute__((address_space(1))) void*)g,
                (__attribute__((address_space(3))) void*)&lds[wv][t * 512],
                16, 0, 0);
        }
        __syncthreads();

        short8 ah[4], al[4];
#pragma unroll
        for (int i = 0; i < 4; ++i) {
            ah[i] = *(const short8*)&lds[0][(ta + i) * 512 + lane * 8];
            al[i] = *(const short8*)&lds[1][(ta + i) * 512 + lane * 8];
        }
#pragma unroll
        for (int j = 0; j < 4; ++j) {
            const short8 bh = *(const short8*)&lds[2][(tb + j) * 512 + lane * 8];
            const short8 bl = *(const short8*)&lds[3][(tb + j) * 512 + lane * 8];
#pragma unroll
            for (int i = 0; i < 4; ++i) {
                acc[i][j] = __builtin_amdgcn_mfma_f32_16x16x32_bf16(ah[i], bh, acc[i][j], 0, 0, 0);
                acc[i][j] = __builtin_amdgcn_mfma_f32_16x16x32_bf16(ah[i], bl, acc[i][j], 0, 0, 0);
                acc[i][j] = __builtin_amdgcn_mfma_f32_16x16x32_bf16(al[i], bh, acc[i][j], 0, 0, 0);
            }
        }
    }

    // Epilogue: sq -> exp2 -> row sums. D layout: col=lane&15, row=q*4+reg.
    const float C2 = (float)(0.5 / 2.50662827463100050242 * 1.44269504088896340736);
#pragma unroll
    for (int i = 0; i < 4; ++i) {
        const int rb = wr + i * 16 + q * 4;
        const float xn0 = xns[rb + 0], xn1 = xns[rb + 1];
        const float xn2 = xns[rb + 2], xn3 = xns[rb + 3];
        float s0 = 0.f, s1 = 0.f, s2 = 0.f, s3 = 0.f;
#pragma unroll
        for (int j = 0; j < 4; ++j) {
            const float dnv = dns[wc + j * 16 + r];
            s0 += __builtin_amdgcn_exp2f(fmaf(-C2, xn0 + dnv - 2.0f * acc[i][j][0], negLogM));
            s1 += __builtin_amdgcn_exp2f(fmaf(-C2, xn1 + dnv - 2.0f * acc[i][j][1], negLogM));
            s2 += __builtin_amdgcn_exp2f(fmaf(-C2, xn2 + dnv - 2.0f * acc[i][j][2], negLogM));
            s3 += __builtin_amdgcn_exp2f(fmaf(-C2, xn3 + dnv - 2.0f * acc[i][j][3], negLogM));
        }
#pragma unroll
        for (int off = 1; off < 16; off <<= 1) {
            s0 += __shfl_xor(s0, off, 64);
            s1 += __shfl_xor(s1, off, 64);
            s2 += __shfl_xor(s2, off, 64);
            s3 += __shfl_xor(s3, off, 64);
        }
        if (r == 0) {
            atomicAdd(&out[rowBase + rb + 0], s0);
            atomicAdd(&out[rowBase + rb + 1], s1);
            atomicAdd(&out[rowBase + rb + 2], s2);
            atomicAdd(&out[rowBase + rb + 3], s3);
        }
    }
}

// ---------------- fallback: round-1 VALU kernel (no workspace needed) -----
#define BN 128
#define BM 128
#define KT 32
#define LDSS 132

__global__ __launch_bounds__(256, 4)
void kde_valu(const float* __restrict__ x, const float* __restrict__ data,
              float* __restrict__ out, int N, int M) {
    __shared__ float xs[KT][LDSS];
    __shared__ float dsh[KT][LDSS];
    __shared__ float xn_s[BN];
    __shared__ float dn_s[BM];
    const int tid = threadIdx.x;
    const int ty = tid >> 4, tx = tid & 15;
    const int rowBase = blockIdx.y * BN, colBase = blockIdx.x * BM;
    float acc[8][8];
#pragma unroll
    for (int i = 0; i < 8; ++i)
#pragma unroll
        for (int j = 0; j < 8; ++j) acc[i][j] = 0.0f;
    float normAcc = 0.0f;
    for (int kc = 0; kc < D_DIM; kc += KT) {
        __syncthreads();
#pragma unroll
        for (int i = 0; i < 4; ++i) {
            const int idx = tid + i * 256;
            const int row = idx >> 3, kq = idx & 7;
            const float4 v = *(const float4*)&x[(size_t)(rowBase + row) * D_DIM + kc + kq * 4];
            xs[kq * 4 + 0][row] = v.x; xs[kq * 4 + 1][row] = v.y;
            xs[kq * 4 + 2][row] = v.z; xs[kq * 4 + 3][row] = v.w;
            const float4 w = *(const float4*)&data[(size_t)(colBase + row) * D_DIM + kc + kq * 4];
            dsh[kq * 4 + 0][row] = w.x; dsh[kq * 4 + 1][row] = w.y;
            dsh[kq * 4 + 2][row] = w.z; dsh[kq * 4 + 3][row] = w.w;
        }
        __syncthreads();
        {
            const float* col = (tid < 128) ? &xs[0][tid] : &dsh[0][tid - 128];
#pragma unroll
            for (int k = 0; k < KT; ++k) { const float v = col[k * LDSS]; normAcc = fmaf(v, v, normAcc); }
        }
#pragma unroll
        for (int k = 0; k < KT; ++k) {
            float a[8], b[8];
            *(float4*)&a[0] = *(const float4*)&xs[k][ty * 8];
            *(float4*)&a[4] = *(const float4*)&xs[k][ty * 8 + 4];
            *(float4*)&b[0] = *(const float4*)&dsh[k][tx * 4];
            *(float4*)&b[4] = *(const float4*)&dsh[k][64 + tx * 4];
#pragma unroll
            for (int i = 0; i < 8; ++i)
#pragma unroll
                for (int j = 0; j < 8; ++j) acc[i][j] = fmaf(a[i], b[j], acc[i][j]);
        }
    }
    if (tid < 128) xn_s[tid] = normAcc; else dn_s[tid - 128] = normAcc;
    __syncthreads();
    const float C2 = (float)(0.5 / 2.50662827463100050242 * 1.44269504088896340736);
    const float negLogM = -log2f((float)M);
#pragma unroll
    for (int i = 0; i < 8; ++i) {
        const int row = ty * 8 + i;
        const float xnr = xn_s[row];
        float s = 0.0f;
#pragma unroll
        for (int j = 0; j < 8; ++j) {
            const int col = (j < 4) ? (tx * 4 + j) : (64 + tx * 4 + (j - 4));
            const float sq = xnr + dn_s[col] - 2.0f * acc[i][j];
            s += exp2f(fmaf(-C2, sq, negLogM));
        }
#pragma unroll
        for (int off = 1; off < 16; off <<= 1) s += __shfl_xor(s, off, 64);
        if (tx == 0) atomicAdd(&out[rowBase + row], s);
    }
}

extern "C" void kernel_launch(void* const* d_in, const int* in_sizes, int n_in,
                              void* d_out, int out_size, void* d_ws, size_t ws_size,
                              hipStream_t stream) {
    const float* x    = (const float*)d_in[0];
    const float* data = (const float*)d_in[1];
    float* out = (float*)d_out;
    const int N = in_sizes[0] / D_DIM;
    const int M = in_sizes[1] / D_DIM;

    hipMemsetAsync(d_out, 0, (size_t)out_size * sizeof(float), stream);

    const size_t need = (size_t)(N + M) * D_DIM * 2 * 2 + (size_t)(N + M) * 4;
    if (ws_size < need || (N & 127) || (M & 127)) {
        dim3 grid(M / BM, N / BN);
        kde_valu<<<grid, 256, 0, stream>>>(x, data, out, N, M);
        return;
    }

    unsigned short* xh = (unsigned short*)d_ws;
    unsigned short* xl = xh + (size_t)N * D_DIM;
    unsigned short* dh = xl + (size_t)N * D_DIM;
    unsigned short* dl = dh + (size_t)M * D_DIM;
    float* xn = (float*)(dl + (size_t)M * D_DIM);
    float* dn = xn + N;

    const int xThreads = N * 32;                 // 32 threads per row
    const int totThreads = (N + M) * 32;
    prep_kernel<<<totThreads / 256, 256, 0, stream>>>(x, data, xh, xl, dh, dl, xn, dn, xThreads);

    dim3 grid(M / 128, N / 128);
    kde_mfma<<<grid, 256, 0, stream>>>(xh, xl, dh, dl, xn, dn, out, -log2f((float)M));
}

// Round 3
// 120.334 us; speedup vs baseline: 2.6504x; 1.2924x over previous
//
#include <hip/hip_runtime.h>
#include <math.h>

// KDE via GEMM trick, MFMA edition v3: persistent-A / streaming-B.
//   density[i] = (1/M) * sum_j exp2(-C2*sq_ij - log2(M)),
//   sq_ij = |x_i|^2 + |d_j|^2 - 2*dot(x_i,d_j),  dot via bf16 split
//   (hi+lo, 3 MFMA passes), norms exact fp32 from prep.
//
// Main kernel: grid = (N/128 row-blocks) x (M/512 col-groups) = 1024 blocks.
// Block = 4 waves; A (128 rows x K=128, hi+lo) loaded ONCE into registers
// (per wave 4 row-tiles x 4 kchunks x 2 = 128 VGPR). B streamed 64 cols/iter
// through double-buffered LDS via global_load_lds (fire-and-forget). Barrier
// at iter top drains the stage issued a full iter ago (free); next stage
// issued after the barrier so vmcnt(0) never waits on live prefetch.
// Epilogue fused per iter; row sums accumulate in registers across iters.
//
// Fragment mappings verified end-to-end in round 2 (passed, absmax 1.7e-18):
//   A: lane holds A[m=lane&15][k=(lane>>4)*8+j]
//   B: lane holds B^T row-major, col=lane&15, k=(lane>>4)*8+j
//   C/D: col=lane&15, row=(lane>>4)*4+reg

#define D_DIM 128

typedef __attribute__((ext_vector_type(8))) short short8;
typedef __attribute__((ext_vector_type(4))) float f32x4;

static __device__ __forceinline__ unsigned short f2bf(float f) {
    unsigned u = __builtin_bit_cast(unsigned, f);
    u += 0x7fffu + ((u >> 16) & 1u);   // RNE
    return (unsigned short)(u >> 16);
}
static __device__ __forceinline__ float bf2f(unsigned short h) {
    unsigned u = ((unsigned)h) << 16;
    return __builtin_bit_cast(float, u);
}

// ---------------- prep: fp32 -> (hi,lo) bf16 + exact fp32 row norms --------
__global__ __launch_bounds__(256)
void prep_kernel(const float* __restrict__ x, const float* __restrict__ data,
                 unsigned short* __restrict__ xh, unsigned short* __restrict__ xl,
                 unsigned short* __restrict__ dh, unsigned short* __restrict__ dl,
                 float* __restrict__ xn, float* __restrict__ dn, int xThreads) {
    const int gid = blockIdx.x * 256 + threadIdx.x;
    const int which = (gid >= xThreads);
    const int id = which ? (gid - xThreads) : gid;
    const int row = id >> 5, seg = id & 31;            // 32 threads per row
    const float* src = which ? data : x;
    unsigned short* hh = which ? dh : xh;
    unsigned short* ll = which ? dl : xl;

    const float4 v = *(const float4*)&src[(size_t)row * D_DIM + seg * 4];
    ushort4 hv, lv;
    hv.x = f2bf(v.x); lv.x = f2bf(v.x - bf2f(hv.x));
    hv.y = f2bf(v.y); lv.y = f2bf(v.y - bf2f(hv.y));
    hv.z = f2bf(v.z); lv.z = f2bf(v.z - bf2f(hv.z));
    hv.w = f2bf(v.w); lv.w = f2bf(v.w - bf2f(hv.w));
    *(ushort4*)&hh[(size_t)row * D_DIM + seg * 4] = hv;
    *(ushort4*)&ll[(size_t)row * D_DIM + seg * 4] = lv;

    float nrm = v.x * v.x + v.y * v.y + v.z * v.z + v.w * v.w;
#pragma unroll
    for (int off = 1; off < 32; off <<= 1) nrm += __shfl_xor(nrm, off, 64);
    if (seg == 0) (which ? dn : xn)[row] = nrm;
}

// ---------------- main MFMA kernel (persistent-A, streaming-B) ------------
__global__ __launch_bounds__(256, 2)
void kde_mfma2(const unsigned short* __restrict__ xh, const unsigned short* __restrict__ xl,
               const unsigned short* __restrict__ dh, const unsigned short* __restrict__ dl,
               const float* __restrict__ xn, const float* __restrict__ dn,
               float* __restrict__ out, int colGroups, float negLogM) {
    // Two 32 KB buffers: prologue holds A (sh[0]=hi, sh[1]=lo, frag=t*4+kc);
    // then both become the B double-buffer (frag = arr*16 + ct*4 + kc).
    __shared__ unsigned short sh[2][16384];
    __shared__ float dns[512];          // -C2 * |d_col|^2 for this block

    const int tid  = threadIdx.x;
    const int lane = tid & 63;
    const int w    = tid >> 6;
    const int q    = lane >> 4;         // 0..3
    const int r    = lane & 15;         // 0..15
    const int wh   = w >> 1;            // row half: rows wh*64..+64
    const int wcl  = w & 1;             // col half: cols wcl*32..+32 per iter

    const int bid = blockIdx.x;
    const int cg  = bid % colGroups;    // consecutive bids -> different XCDs,
    const int rb  = bid / colGroups;    // same cg recurs every 8/16 -> L2 reuse
    const int rowBase = rb * 128;
    const int colBase = cg * 512;

    const float C2 = (float)(0.5 / 2.50662827463100050242 * 1.44269504088896340736);
    const float twoC2 = 2.0f * C2;

    // Pre-scaled column norms for this block's 512 cols.
    dns[tid]       = -C2 * dn[colBase + tid];
    dns[tid + 256] = -C2 * dn[colBase + 256 + tid];

    // Per-lane row constants: u = -C2*|x_row|^2 + negLogM for the 16 rows
    // this lane's accumulators cover (4 row-tiles x 4 regs).
    float u[4][4];
#pragma unroll
    for (int ri = 0; ri < 4; ++ri)
#pragma unroll
        for (int p = 0; p < 4; ++p)
            u[ri][p] = fmaf(-C2, xn[rowBase + wh * 64 + ri * 16 + q * 4 + p], negLogM);

    // ---- stage A once: wave w stages row-tiles {2w, 2w+1}, hi+lo, 4 kchunks
#pragma unroll
    for (int ri2 = 0; ri2 < 2; ++ri2) {
        const int t = 2 * w + ri2;
#pragma unroll
        for (int kc = 0; kc < 4; ++kc) {
            const unsigned short* gh = &xh[(size_t)(rowBase + t * 16 + r) * D_DIM + kc * 32 + q * 8];
            const unsigned short* gl = &xl[(size_t)(rowBase + t * 16 + r) * D_DIM + kc * 32 + q * 8];
            __builtin_amdgcn_global_load_lds(
                (const __attribute__((address_space(1))) void*)gh,
                (__attribute__((address_space(3))) void*)&sh[0][(t * 4 + kc) * 512], 16, 0, 0);
            __builtin_amdgcn_global_load_lds(
                (const __attribute__((address_space(1))) void*)gl,
                (__attribute__((address_space(3))) void*)&sh[1][(t * 4 + kc) * 512], 16, 0, 0);
        }
    }
    __syncthreads();

    // ---- A fragments to registers: 4 row-tiles (this wave's 64 rows) x 4 kc
    short8 ah[4][4], al[4][4];
#pragma unroll
    for (int ri = 0; ri < 4; ++ri) {
        const int t = wh * 4 + ri;
#pragma unroll
        for (int kc = 0; kc < 4; ++kc) {
            ah[ri][kc] = *(const short8*)&sh[0][(t * 4 + kc) * 512 + lane * 8];
            al[ri][kc] = *(const short8*)&sh[1][(t * 4 + kc) * 512 + lane * 8];
        }
    }
    __syncthreads();   // everyone done reading A before B overwrites

    // B stage: 32 frags (arr*16 + ct*4 + kc), 8 per wave, fire-and-forget.
    auto stageB = [&](int nit, int buf) {
#pragma unroll
        for (int i = 0; i < 8; ++i) {
            const int f = w * 8 + i;
            const int arr = f >> 4, ct = (f >> 2) & 3, kc = f & 3;
            const unsigned short* src = arr ? dl : dh;
            const unsigned short* g =
                &src[(size_t)(colBase + nit * 64 + ct * 16 + r) * D_DIM + kc * 32 + q * 8];
            __builtin_amdgcn_global_load_lds(
                (const __attribute__((address_space(1))) void*)g,
                (__attribute__((address_space(3))) void*)&sh[buf][f * 512], 16, 0, 0);
        }
    };

    stageB(0, 0);

    float srow[4][4];
#pragma unroll
    for (int ri = 0; ri < 4; ++ri)
#pragma unroll
        for (int p = 0; p < 4; ++p) srow[ri][p] = 0.0f;

    const int NIT = 8;  // 512 cols / 64
    for (int it = 0; it < NIT; ++it) {
        __syncthreads();               // drains stage(it) (issued a full iter ago)
        const int cur = it & 1;
        if (it + 1 < NIT) stageB(it + 1, cur ^ 1);   // overlaps this iter's compute

#pragma unroll
        for (int ctl = 0; ctl < 2; ++ctl) {
            const int ct = wcl * 2 + ctl;
            short8 bh[4], bl[4];
#pragma unroll
            for (int kc = 0; kc < 4; ++kc) {
                bh[kc] = *(const short8*)&sh[cur][(ct * 4 + kc) * 512 + lane * 8];
                bl[kc] = *(const short8*)&sh[cur][((16 + ct * 4 + kc)) * 512 + lane * 8];
            }
            f32x4 acc[4];
#pragma unroll
            for (int ri = 0; ri < 4; ++ri) acc[ri] = (f32x4){0.f, 0.f, 0.f, 0.f};
#pragma unroll
            for (int kc = 0; kc < 4; ++kc)
#pragma unroll
                for (int ri = 0; ri < 4; ++ri) {
                    acc[ri] = __builtin_amdgcn_mfma_f32_16x16x32_bf16(ah[ri][kc], bh[kc], acc[ri], 0, 0, 0);
                    acc[ri] = __builtin_amdgcn_mfma_f32_16x16x32_bf16(ah[ri][kc], bl[kc], acc[ri], 0, 0, 0);
                    acc[ri] = __builtin_amdgcn_mfma_f32_16x16x32_bf16(al[ri][kc], bh[kc], acc[ri], 0, 0, 0);
                }
            const float dnv = dns[it * 64 + ct * 16 + r];
#pragma unroll
            for (int ri = 0; ri < 4; ++ri) {
                const float u0 = u[ri][0] + dnv, u1 = u[ri][1] + dnv;
                const float u2 = u[ri][2] + dnv, u3 = u[ri][3] + dnv;
                srow[ri][0] += __builtin_amdgcn_exp2f(fmaf(twoC2, acc[ri][0], u0));
                srow[ri][1] += __builtin_amdgcn_exp2f(fmaf(twoC2, acc[ri][1], u1));
                srow[ri][2] += __builtin_amdgcn_exp2f(fmaf(twoC2, acc[ri][2], u2));
                srow[ri][3] += __builtin_amdgcn_exp2f(fmaf(twoC2, acc[ri][3], u3));
            }
        }
    }

    // Final: reduce each srow over the 16 col-lanes (r) and atomically add.
#pragma unroll
    for (int ri = 0; ri < 4; ++ri)
#pragma unroll
        for (int p = 0; p < 4; ++p) {
            float s = srow[ri][p];
#pragma unroll
            for (int off = 1; off < 16; off <<= 1) s += __shfl_xor(s, off, 64);
            if (r == 0)
                atomicAdd(&out[rowBase + wh * 64 + ri * 16 + q * 4 + p], s);
        }
}

// ---------------- fallback: round-1 VALU kernel ---------------------------
#define BN 128
#define BM 128
#define KT 32
#define LDSS 132

__global__ __launch_bounds__(256, 4)
void kde_valu(const float* __restrict__ x, const float* __restrict__ data,
              float* __restrict__ out, int N, int M) {
    __shared__ float xs[KT][LDSS];
    __shared__ float dsh[KT][LDSS];
    __shared__ float xn_s[BN];
    __shared__ float dn_s[BM];
    const int tid = threadIdx.x;
    const int ty = tid >> 4, tx = tid & 15;
    const int rowBase = blockIdx.y * BN, colBase = blockIdx.x * BM;
    float acc[8][8];
#pragma unroll
    for (int i = 0; i < 8; ++i)
#pragma unroll
        for (int j = 0; j < 8; ++j) acc[i][j] = 0.0f;
    float normAcc = 0.0f;
    for (int kc = 0; kc < D_DIM; kc += KT) {
        __syncthreads();
#pragma unroll
        for (int i = 0; i < 4; ++i) {
            const int idx = tid + i * 256;
            const int row = idx >> 3, kq = idx & 7;
            const float4 v = *(const float4*)&x[(size_t)(rowBase + row) * D_DIM + kc + kq * 4];
            xs[kq * 4 + 0][row] = v.x; xs[kq * 4 + 1][row] = v.y;
            xs[kq * 4 + 2][row] = v.z; xs[kq * 4 + 3][row] = v.w;
            const float4 wv = *(const float4*)&data[(size_t)(colBase + row) * D_DIM + kc + kq * 4];
            dsh[kq * 4 + 0][row] = wv.x; dsh[kq * 4 + 1][row] = wv.y;
            dsh[kq * 4 + 2][row] = wv.z; dsh[kq * 4 + 3][row] = wv.w;
        }
        __syncthreads();
        {
            const float* col = (tid < 128) ? &xs[0][tid] : &dsh[0][tid - 128];
#pragma unroll
            for (int k = 0; k < KT; ++k) { const float v = col[k * LDSS]; normAcc = fmaf(v, v, normAcc); }
        }
#pragma unroll
        for (int k = 0; k < KT; ++k) {
            float a[8], b[8];
            *(float4*)&a[0] = *(const float4*)&xs[k][ty * 8];
            *(float4*)&a[4] = *(const float4*)&xs[k][ty * 8 + 4];
            *(float4*)&b[0] = *(const float4*)&dsh[k][tx * 4];
            *(float4*)&b[4] = *(const float4*)&dsh[k][64 + tx * 4];
#pragma unroll
            for (int i = 0; i < 8; ++i)
#pragma unroll
                for (int j = 0; j < 8; ++j) acc[i][j] = fmaf(a[i], b[j], acc[i][j]);
        }
    }
    if (tid < 128) xn_s[tid] = normAcc; else dn_s[tid - 128] = normAcc;
    __syncthreads();
    const float C2 = (float)(0.5 / 2.50662827463100050242 * 1.44269504088896340736);
    const float negLogM = -log2f((float)M);
#pragma unroll
    for (int i = 0; i < 8; ++i) {
        const int row = ty * 8 + i;
        const float xnr = xn_s[row];
        float s = 0.0f;
#pragma unroll
        for (int j = 0; j < 8; ++j) {
            const int col = (j < 4) ? (tx * 4 + j) : (64 + tx * 4 + (j - 4));
            const float sq = xnr + dn_s[col] - 2.0f * acc[i][j];
            s += exp2f(fmaf(-C2, sq, negLogM));
        }
#pragma unroll
        for (int off = 1; off < 16; off <<= 1) s += __shfl_xor(s, off, 64);
        if (tx == 0) atomicAdd(&out[rowBase + row], s);
    }
}

extern "C" void kernel_launch(void* const* d_in, const int* in_sizes, int n_in,
                              void* d_out, int out_size, void* d_ws, size_t ws_size,
                              hipStream_t stream) {
    const float* x    = (const float*)d_in[0];
    const float* data = (const float*)d_in[1];
    float* out = (float*)d_out;
    const int N = in_sizes[0] / D_DIM;
    const int M = in_sizes[1] / D_DIM;

    hipMemsetAsync(d_out, 0, (size_t)out_size * sizeof(float), stream);

    const size_t need = (size_t)(N + M) * D_DIM * 2 * 2 + (size_t)(N + M) * 4;
    if (ws_size < need || (N & 127) || (M & 511)) {
        dim3 grid(M / BM, N / BN);
        kde_valu<<<grid, 256, 0, stream>>>(x, data, out, N, M);
        return;
    }

    unsigned short* xh = (unsigned short*)d_ws;
    unsigned short* xl = xh + (size_t)N * D_DIM;
    unsigned short* dh = xl + (size_t)N * D_DIM;
    unsigned short* dl = dh + (size_t)M * D_DIM;
    float* xn = (float*)(dl + (size_t)M * D_DIM);
    float* dn = xn + N;

    const int xThreads = N * 32;
    const int totThreads = (N + M) * 32;
    prep_kernel<<<totThreads / 256, 256, 0, stream>>>(x, data, xh, xl, dh, dl, xn, dn, xThreads);

    const int colGroups = M / 512;
    const int rowBlocks = N / 128;
    kde_mfma2<<<rowBlocks * colGroups, 256, 0, stream>>>(xh, xl, dh, dl, xn, dn, out,
                                                         colGroups, -log2f((float)M));
}